// Round 7
// baseline (181.906 us; speedup 1.0000x reference)
//
#include <hip/hip_runtime.h>
#include <cstdint>

#define EPSV 1e-5f
#define SM_SCALE 0.044194173824159216f

typedef unsigned short u16;
typedef __attribute__((ext_vector_type(8))) short short8;
typedef __attribute__((ext_vector_type(4))) float f32x4;
typedef __attribute__((ext_vector_type(4))) unsigned short us4;

__device__ __forceinline__ u16 f2bf(float f) {
  union { float f; uint32_t u; } v; v.f = f;
  return (u16)((v.u + 0x7FFFu + ((v.u >> 16) & 1u)) >> 16);
}

__device__ __forceinline__ void gload_lds16(const void* g, void* l) {
  __builtin_amdgcn_global_load_lds((const __attribute__((address_space(1))) void*)g,
                                   (__attribute__((address_space(3))) void*)l, 16, 0, 0);
}

__device__ __forceinline__ f32x4 mfma16(short8 a, short8 b, f32x4 c) {
  return __builtin_amdgcn_mfma_f32_16x16x32_bf16(a, b, c, 0, 0, 0);
}

// Swizzled LDS tile: [rows][32 bf16] (64B rows). 16B-slot s of row r holds the
// global 16B-block (s ^ ((r>>1)&3)). Staged with linear LDS dest + permuted
// GLOBAL source; read with the same XOR (verified conflict-free: R6 PMC = 0).
__device__ __forceinline__ const short8* lds_frag(const u16* t, int row, int cc) {
  return reinterpret_cast<const short8*>(t + (size_t)(((row << 2) + (cc ^ ((row >> 1) & 3))) << 3));
}

// Counted-vmcnt barrier pair (depth-2 users): keep newest stage in flight.
#define WAIT_ENTER(N, is_tail)                                      \
  if (is_tail) { asm volatile("s_waitcnt vmcnt(0)" ::: "memory"); } \
  else         { asm volatile("s_waitcnt vmcnt(" #N ")" ::: "memory"); } \
  __builtin_amdgcn_s_barrier();                                     \
  asm volatile("" ::: "memory");

#define WAIT_EXIT()                                                 \
  asm volatile("s_waitcnt lgkmcnt(0)" ::: "memory");                \
  __builtin_amdgcn_s_barrier();                                     \
  asm volatile("" ::: "memory");

// ---------- Fused GroupNorm (stats + apply in one pass via LDS) ----------
__global__ __launch_bounds__(256) void gn_fused_k(const float* __restrict__ x,
                                                  const float* __restrict__ gw,
                                                  const float* __restrict__ gb,
                                                  u16* __restrict__ xn) {
  __shared__ float xs[8192];
  __shared__ float ls[4], lss[4];
  const int bg = blockIdx.x;                     // 0..2047
  const int g = bg & 31;
  const float* p = x + (size_t)bg * 8192;
  float s = 0.f, ss = 0.f;
#pragma unroll
  for (int i = 0; i < 8; ++i) {
    const int idx = i * 1024 + threadIdx.x * 4;
    float4 v = *reinterpret_cast<const float4*>(p + idx);
    *reinterpret_cast<float4*>(xs + idx) = v;
    s += v.x + v.y + v.z + v.w;
    ss += v.x * v.x + v.y * v.y + v.z * v.z + v.w * v.w;
  }
  for (int off = 32; off; off >>= 1) { s += __shfl_xor(s, off); ss += __shfl_xor(ss, off); }
  const int w = threadIdx.x >> 6;
  if ((threadIdx.x & 63) == 0) { ls[w] = s; lss[w] = ss; }
  __syncthreads();
  s = ls[0] + ls[1] + ls[2] + ls[3];
  ss = lss[0] + lss[1] + lss[2] + lss[3];
  const float inv_n = 1.0f / 8192.f;
  const float mean = s * inv_n;
  const float rstd = rsqrtf(ss * inv_n - mean * mean + EPSV);
#pragma unroll
  for (int j = 0; j < 4; ++j) {
    const int idx = j * 2048 + threadIdx.x * 8;
    const int c = g * 16 + (idx >> 9);
    const float sc = gw[c] * rstd;
    const float sh = gb[c] - mean * sc;
    u16 o[8];
#pragma unroll
    for (int e = 0; e < 8; ++e) o[e] = f2bf(xs[idx + e] * sc + sh);
    *reinterpret_cast<uint4*>(xn + (size_t)bg * 8192 + idx) = *reinterpret_cast<const uint4*>(o);
  }
}

// ---------- fp32 -> bf16 cast for the 3 weight matrices ----------
__global__ __launch_bounds__(256) void cast3_k(const float* __restrict__ a,
                                               const float* __restrict__ b2,
                                               const float* __restrict__ c,
                                               u16* __restrict__ oa, u16* __restrict__ ob,
                                               u16* __restrict__ oc) {
  const int which = blockIdx.x >> 7;
  const float* in = which == 0 ? a : (which == 1 ? b2 : c);
  u16* out = which == 0 ? oa : (which == 1 ? ob : oc);
  size_t base = (((size_t)(blockIdx.x & 127)) * 256 + threadIdx.x) * 8;
  float4 v0 = *reinterpret_cast<const float4*>(in + base);
  float4 v1 = *reinterpret_cast<const float4*>(in + base + 4);
  u16 o[8];
  o[0] = f2bf(v0.x); o[1] = f2bf(v0.y); o[2] = f2bf(v0.z); o[3] = f2bf(v0.w);
  o[4] = f2bf(v1.x); o[5] = f2bf(v1.y); o[6] = f2bf(v1.z); o[7] = f2bf(v1.w);
  *reinterpret_cast<uint4*>(out + base) = *reinterpret_cast<const uint4*>(o);
}

// ---------- Fused QKV GEMM: 4 waves, 64x64/wave/matrix, swizzled, depth-3 ----------
// Q = xn qw^T + qb ; K likewise ; V stored transposed VT[b,n,m].
// R5 geometry (MFMA:ds_read = 3.0) + R6 swizzle (conflict-free) + 3-deep pipeline.
__global__ __launch_bounds__(256, 1) void qkv_fused_k(
    const u16* __restrict__ xn, const u16* __restrict__ qw,
    const u16* __restrict__ kw, const u16* __restrict__ vw,
    const float* __restrict__ qb, const float* __restrict__ kb,
    const float* __restrict__ vb,
    u16* __restrict__ Q, u16* __restrict__ K, u16* __restrict__ VT) {
  __shared__ u16 As[3][4096];
  __shared__ u16 Bq[3][4096], Bk[3][4096], Bv[3][4096];   // 96 KB total
  const int d = blockIdx.x;
  const int t = d >> 3;
  const int b = (d & 7) * 8 + (t >> 4);          // XCD-bijective batch
  const int tile = t & 15;
  const int tm = (tile >> 2) * 128, tn = (tile & 3) * 128;
  const u16* Ab = xn + (size_t)b * 262144;
  const int tid = threadIdx.x, w = tid >> 6, lane = tid & 63;
  const int wr = (w >> 1) * 64, wc = (w & 1) * 64;
  const int srow = lane >> 2;
  const int ssw = ((lane & 3) ^ ((lane >> 3) & 3)) * 8;   // inverse-swizzled src col
  f32x4 acc[3][4][4] = {};

  // 8 chunks of 16 rows x 32 cols per matrix; 8 loads/thread per stage.
#define QKV_STAGE(bb, k0)                                                      \
  {                                                                            \
    _Pragma("unroll")                                                          \
    for (int i = 0; i < 2; ++i) {                                              \
      const int ch = w + i * 4;                                                \
      const size_t gro = (size_t)(ch * 16 + srow) * 512 + (k0) + ssw;          \
      gload_lds16(Ab + (size_t)tm * 512 + gro, &As[bb][ch * 512]);             \
      gload_lds16(qw + (size_t)tn * 512 + gro, &Bq[bb][ch * 512]);             \
      gload_lds16(kw + (size_t)tn * 512 + gro, &Bk[bb][ch * 512]);             \
      gload_lds16(vw + (size_t)tn * 512 + gro, &Bv[bb][ch * 512]);             \
    }                                                                          \
  }

  QKV_STAGE(0, 0);      // 8 loads/thread
  QKV_STAGE(1, 32);     // 16 in flight
  QKV_STAGE(2, 64);     // 24 in flight
  for (int ts = 0; ts < 16; ++ts) {
    const int cur = ts % 3;
    if (ts < 14)       { asm volatile("s_waitcnt vmcnt(16)" ::: "memory"); }
    else if (ts == 14) { asm volatile("s_waitcnt vmcnt(8)" ::: "memory"); }
    else               { asm volatile("s_waitcnt vmcnt(0)" ::: "memory"); }
    __builtin_amdgcn_s_barrier();
    asm volatile("" ::: "memory");
    const int frow = lane & 15, cc = lane >> 4;
    short8 af[4], b0[4], b1[4], b2[4];
#pragma unroll
    for (int i = 0; i < 4; ++i)
      af[i] = *lds_frag(As[cur], wr + i * 16 + frow, cc);
#pragma unroll
    for (int j = 0; j < 4; ++j) {
      const int br = wc + j * 16 + frow;
      b0[j] = *lds_frag(Bq[cur], br, cc);
      b1[j] = *lds_frag(Bk[cur], br, cc);
      b2[j] = *lds_frag(Bv[cur], br, cc);
    }
#pragma unroll
    for (int i = 0; i < 4; ++i)
#pragma unroll
      for (int j = 0; j < 4; ++j) {
        acc[0][i][j] = mfma16(af[i], b0[j], acc[0][i][j]);
        acc[1][i][j] = mfma16(af[i], b1[j], acc[1][i][j]);
        acc[2][i][j] = mfma16(af[i], b2[j], acc[2][i][j]);
      }
    WAIT_EXIT();
    if (ts < 13) QKV_STAGE(cur, (ts + 3) * 32);
  }
#undef QKV_STAGE

  const int col0 = lane & 15, row0 = (lane >> 4) * 4;
#pragma unroll
  for (int i = 0; i < 4; ++i) {
#pragma unroll
    for (int j = 0; j < 4; ++j) {
      const int gc = tn + wc + j * 16 + col0;
      const int gr0 = tm + wr + i * 16 + row0;
      const float qbv = qb[gc], kbv = kb[gc], vbv = vb[gc];
      us4 vt;
#pragma unroll
      for (int r = 0; r < 4; ++r) {
        const size_t o = (size_t)b * 262144 + (size_t)(gr0 + r) * 512 + gc;
        Q[o] = f2bf(acc[0][i][j][r] + qbv);
        K[o] = f2bf(acc[1][i][j][r] + kbv);
        vt[r] = f2bf(acc[2][i][j][r] + vbv);
      }
      *reinterpret_cast<us4*>(&VT[(size_t)b * 262144 + (size_t)gc * 512 + gr0]) = vt;
    }
  }
}

// ---------- scores + softmax -> P: 8 waves = 2 qhalf x 4 kquad ----------
__global__ __launch_bounds__(512, 2) void scores_softmax_k(const u16* __restrict__ Q,
                                                           const u16* __restrict__ K,
                                                           u16* __restrict__ P) {
  __shared__ u16 Qs[2][4096];     // 128 rows x 32
  __shared__ u16 Ks[2][16384];    // 512 rows x 32
  __shared__ float rmax[4][128], rsum[4][128];
  const int d = blockIdx.x;       // 0..255
  const int t = d >> 3;
  const int b = (d & 7) * 8 + (t >> 2);
  const int m0 = (t & 3) * 128;
  const u16* Qb = Q + (size_t)b * 262144 + (size_t)m0 * 512;
  const u16* Kb = K + (size_t)b * 262144;
  u16* Pb = P + (size_t)b * 262144;
  const int tid = threadIdx.x, wid = tid >> 6, lane = tid & 63;
  const int qh = wid >> 2, kq = wid & 3;
  const int srow = lane >> 2;
  const int ssw = ((lane & 3) ^ ((lane >> 3) & 3)) * 8;
  f32x4 acc[4][8] = {};           // [i<4 rowfrag][j<8 keyfrag]

#define SC_STAGE(bb, k0)                                                       \
  {                                                                            \
    _Pragma("unroll")                                                          \
    for (int s2 = 0; s2 < 5; ++s2) {                                           \
      const int c = wid * 5 + s2;                                              \
      if (c < 8)                                                               \
        gload_lds16(Qb + (size_t)(c * 16 + srow) * 512 + (k0) + ssw,           \
                    &Qs[bb][c * 512]);                                         \
      else                                                                     \
        gload_lds16(Kb + (size_t)((c - 8) * 16 + srow) * 512 + (k0) + ssw,     \
                    &Ks[bb][(c - 8) * 512]);                                   \
    }                                                                          \
  }

  SC_STAGE(0, 0);       // 5 loads/thread
  SC_STAGE(1, 32);      // 10 in flight
  for (int ts = 0; ts < 16; ++ts) {
    const int cur = ts & 1;
    WAIT_ENTER(5, ts == 15);
    const int frow = lane & 15, cc = lane >> 4;
    short8 aq[4];
#pragma unroll
    for (int i = 0; i < 4; ++i)
      aq[i] = *lds_frag(Qs[cur], qh * 64 + i * 16 + frow, cc);
#pragma unroll
    for (int j = 0; j < 8; ++j) {
      short8 bk = *lds_frag(Ks[cur], kq * 128 + j * 16 + frow, cc);
#pragma unroll
      for (int i = 0; i < 4; ++i)
        acc[i][j] = mfma16(aq[i], bk, acc[i][j]);
    }
    WAIT_EXIT();
    if (ts < 14) SC_STAGE(cur, (ts + 2) * 32);
  }
#undef SC_STAGE

  float pm[4][4];
#pragma unroll
  for (int i = 0; i < 4; ++i)
#pragma unroll
    for (int r = 0; r < 4; ++r) pm[i][r] = -1e30f;
#pragma unroll
  for (int i = 0; i < 4; ++i)
#pragma unroll
    for (int j = 0; j < 8; ++j)
#pragma unroll
      for (int r = 0; r < 4; ++r) {
        float v = acc[i][j][r] * SM_SCALE;
        acc[i][j][r] = v;
        pm[i][r] = fmaxf(pm[i][r], v);
      }
#pragma unroll
  for (int off = 1; off < 16; off <<= 1)
#pragma unroll
    for (int i = 0; i < 4; ++i)
#pragma unroll
      for (int r = 0; r < 4; ++r) pm[i][r] = fmaxf(pm[i][r], __shfl_xor(pm[i][r], off));
  if ((lane & 15) == 0) {
#pragma unroll
    for (int i = 0; i < 4; ++i)
#pragma unroll
      for (int r = 0; r < 4; ++r)
        rmax[kq][qh * 64 + i * 16 + (lane >> 4) * 4 + r] = pm[i][r];
  }
  __syncthreads();
#pragma unroll
  for (int i = 0; i < 4; ++i)
#pragma unroll
    for (int r = 0; r < 4; ++r) {
      const int row = qh * 64 + i * 16 + (lane >> 4) * 4 + r;
      pm[i][r] = fmaxf(fmaxf(rmax[0][row], rmax[1][row]), fmaxf(rmax[2][row], rmax[3][row]));
    }
  float ps[4][4];
#pragma unroll
  for (int i = 0; i < 4; ++i)
#pragma unroll
    for (int r = 0; r < 4; ++r) ps[i][r] = 0.f;
#pragma unroll
  for (int i = 0; i < 4; ++i)
#pragma unroll
    for (int j = 0; j < 8; ++j)
#pragma unroll
      for (int r = 0; r < 4; ++r) {
        float e = __expf(acc[i][j][r] - pm[i][r]);
        acc[i][j][r] = e;
        ps[i][r] += e;
      }
#pragma unroll
  for (int off = 1; off < 16; off <<= 1)
#pragma unroll
    for (int i = 0; i < 4; ++i)
#pragma unroll
      for (int r = 0; r < 4; ++r) ps[i][r] += __shfl_xor(ps[i][r], off);
  if ((lane & 15) == 0) {
#pragma unroll
    for (int i = 0; i < 4; ++i)
#pragma unroll
      for (int r = 0; r < 4; ++r)
        rsum[kq][qh * 64 + i * 16 + (lane >> 4) * 4 + r] = ps[i][r];
  }
  __syncthreads();
#pragma unroll
  for (int i = 0; i < 4; ++i)
#pragma unroll
    for (int r = 0; r < 4; ++r) {
      const int row = qh * 64 + i * 16 + (lane >> 4) * 4 + r;
      ps[i][r] = 1.0f / (rsum[0][row] + rsum[1][row] + rsum[2][row] + rsum[3][row]);
    }
#pragma unroll
  for (int i = 0; i < 4; ++i)
#pragma unroll
    for (int j = 0; j < 8; ++j) {
      const int gcol = kq * 128 + j * 16 + (lane & 15);
#pragma unroll
      for (int r = 0; r < 4; ++r) {
        const int grow = m0 + qh * 64 + i * 16 + (lane >> 4) * 4 + r;
        Pb[(size_t)grow * 512 + gcol] = f2bf(acc[i][j][r] * ps[i][r]);
      }
    }
}

// ---------- PV GEMM: out[m,n] = sum_k P[m,k]*VT[n,k] (f32), swizzled ----------
__global__ __launch_bounds__(256, 2) void pv_gemm_k(const u16* __restrict__ P,
                                                    const u16* __restrict__ VT,
                                                    float* __restrict__ out) {
  __shared__ u16 As[2][4096];
  __shared__ u16 Bs[2][4096];     // 32 KB
  const int d = blockIdx.x;
  const int t = d >> 3;
  const int b = (d & 7) * 8 + (t >> 4);
  const int tile = t & 15;
  const int tm = (tile >> 2) * 128, tn = (tile & 3) * 128;
  const u16* Ab = P + (size_t)b * 262144;
  const u16* Bb = VT + (size_t)b * 262144;
  const int tid = threadIdx.x, w = tid >> 6, lane = tid & 63;
  const int wr = (w >> 1) * 64, wc = (w & 1) * 64;
  const int srow = lane >> 2;
  const int ssw = ((lane & 3) ^ ((lane >> 3) & 3)) * 8;
  f32x4 acc[4][4] = {};

#define PV_STAGE(bb, k0)                                                       \
  {                                                                            \
    _Pragma("unroll")                                                          \
    for (int s2 = 0; s2 < 4; ++s2) {                                           \
      const int c = w * 4 + s2;                                                \
      if (c < 8)                                                               \
        gload_lds16(Ab + (size_t)(tm + c * 16 + srow) * 512 + (k0) + ssw,      \
                    &As[bb][c * 512]);                                         \
      else                                                                     \
        gload_lds16(Bb + (size_t)(tn + (c - 8) * 16 + srow) * 512 + (k0) + ssw,\
                    &Bs[bb][(c - 8) * 512]);                                   \
    }                                                                          \
  }

  PV_STAGE(0, 0);       // 4 loads/thread
  PV_STAGE(1, 32);      // 8 in flight
  for (int ts = 0; ts < 16; ++ts) {
    const int cur = ts & 1;
    WAIT_ENTER(4, ts == 15);
    const int frow = lane & 15, cc = lane >> 4;
    short8 af[4], bf[4];
#pragma unroll
    for (int i = 0; i < 4; ++i) {
      af[i] = *lds_frag(As[cur], wr + i * 16 + frow, cc);
      bf[i] = *lds_frag(Bs[cur], wc + i * 16 + frow, cc);
    }
#pragma unroll
    for (int mi = 0; mi < 4; ++mi)
#pragma unroll
      for (int ni = 0; ni < 4; ++ni)
        acc[mi][ni] = mfma16(af[mi], bf[ni], acc[mi][ni]);
    WAIT_EXIT();
    if (ts < 14) PV_STAGE(cur, (ts + 2) * 32);
  }
#undef PV_STAGE

  const int col0 = lane & 15, row0 = (lane >> 4) * 4;
#pragma unroll
  for (int mi = 0; mi < 4; ++mi)
#pragma unroll
    for (int ni = 0; ni < 4; ++ni) {
      const int gc = tn + wc + ni * 16 + col0;
#pragma unroll
      for (int r = 0; r < 4; ++r) {
        const int gr = tm + wr + mi * 16 + row0 + r;
        out[(size_t)b * 262144 + (size_t)gr * 512 + gc] = acc[mi][ni][r];
      }
    }
}

extern "C" void kernel_launch(void* const* d_in, const int* in_sizes, int n_in,
                              void* d_out, int out_size, void* d_ws, size_t ws_size,
                              hipStream_t stream) {
  const float* x = (const float*)d_in[0];
  const float* qw = (const float*)d_in[1];
  const float* qb = (const float*)d_in[2];
  const float* kw = (const float*)d_in[3];
  const float* kb = (const float*)d_in[4];
  const float* vw = (const float*)d_in[5];
  const float* vb = (const float*)d_in[6];
  const float* gnw = (const float*)d_in[7];
  const float* gnb = (const float*)d_in[8];

  char* ws = (char*)d_ws;
  u16* qwb = (u16*)(ws);
  u16* kwb = (u16*)(ws + 524288);
  u16* vwb = (u16*)(ws + 2 * 524288);
  u16* xn = (u16*)(ws + 4 * 524288);
  u16* Qb = xn + 16777216;
  u16* Kb = Qb + 16777216;
  u16* VT = Kb + 16777216;
  u16* P = xn;                       // xn dead after QKV
  float* out = (float*)d_out;

  gn_fused_k<<<dim3(2048), dim3(256), 0, stream>>>(x, gnw, gnb, xn);
  cast3_k<<<dim3(384), dim3(256), 0, stream>>>(qw, kw, vw, qwb, kwb, vwb);
  qkv_fused_k<<<dim3(1024), dim3(256), 0, stream>>>(xn, qwb, kwb, vwb, qb, kb, vb, Qb, Kb, VT);
  scores_softmax_k<<<dim3(256), dim3(512), 0, stream>>>(Qb, Kb, P);
  pv_gemm_k<<<dim3(1024), dim3(256), 0, stream>>>(P, VT, out);
}

// Round 9
// 165.559 us; speedup vs baseline: 1.0987x; 1.0987x over previous
//
#include <hip/hip_runtime.h>
#include <cstdint>

#define EPSV 1e-5f
#define SM_SCALE 0.044194173824159216f

typedef unsigned short u16;
typedef __attribute__((ext_vector_type(8))) short short8;
typedef __attribute__((ext_vector_type(4))) float f32x4;

__device__ __forceinline__ u16 f2bf(float f) {
  union { float f; uint32_t u; } v; v.f = f;
  return (u16)((v.u + 0x7FFFu + ((v.u >> 16) & 1u)) >> 16);
}

__device__ __forceinline__ void gload_lds16(const void* g, void* l) {
  __builtin_amdgcn_global_load_lds((const __attribute__((address_space(1))) void*)g,
                                   (__attribute__((address_space(3))) void*)l, 16, 0, 0);
}

__device__ __forceinline__ f32x4 mfma16(short8 a, short8 b, f32x4 c) {
  return __builtin_amdgcn_mfma_f32_16x16x32_bf16(a, b, c, 0, 0, 0);
}

// Swizzled LDS tile: [rows][32 bf16] (64B rows). 16B-slot s of row r holds
// global block (s ^ ((r>>1)&3)). Linear LDS dest + permuted GLOBAL source;
// read with same XOR. Verified conflict-free (R6/R7 PMC = 0).
__device__ __forceinline__ const short8* lds_frag(const u16* t, int row, int cc) {
  return reinterpret_cast<const short8*>(t + (size_t)(((row << 2) + (cc ^ ((row >> 1) & 3))) << 3));
}

#define WAIT_ENTER(N, is_tail)                                      \
  if (is_tail) { asm volatile("s_waitcnt vmcnt(0)" ::: "memory"); } \
  else         { asm volatile("s_waitcnt vmcnt(" #N ")" ::: "memory"); } \
  __builtin_amdgcn_s_barrier();                                     \
  asm volatile("" ::: "memory");

#define WAIT_EXIT()                                                 \
  asm volatile("s_waitcnt lgkmcnt(0)" ::: "memory");                \
  __builtin_amdgcn_s_barrier();                                     \
  asm volatile("" ::: "memory");

// ---------- Fused GroupNorm (stats + apply in one pass via LDS) ----------
__global__ __launch_bounds__(256) void gn_fused_k(const float* __restrict__ x,
                                                  const float* __restrict__ gw,
                                                  const float* __restrict__ gb,
                                                  u16* __restrict__ xn) {
  __shared__ float xs[8192];
  __shared__ float ls[4], lss[4];
  const int bg = blockIdx.x;                     // 0..2047
  const int g = bg & 31;
  const float* p = x + (size_t)bg * 8192;
  float s = 0.f, ss = 0.f;
#pragma unroll
  for (int i = 0; i < 8; ++i) {
    const int idx = i * 1024 + threadIdx.x * 4;
    float4 v = *reinterpret_cast<const float4*>(p + idx);
    *reinterpret_cast<float4*>(xs + idx) = v;
    s += v.x + v.y + v.z + v.w;
    ss += v.x * v.x + v.y * v.y + v.z * v.z + v.w * v.w;
  }
  for (int off = 32; off; off >>= 1) { s += __shfl_xor(s, off); ss += __shfl_xor(ss, off); }
  const int w = threadIdx.x >> 6;
  if ((threadIdx.x & 63) == 0) { ls[w] = s; lss[w] = ss; }
  __syncthreads();
  s = ls[0] + ls[1] + ls[2] + ls[3];
  ss = lss[0] + lss[1] + lss[2] + lss[3];
  const float inv_n = 1.0f / 8192.f;
  const float mean = s * inv_n;
  const float rstd = rsqrtf(ss * inv_n - mean * mean + EPSV);
#pragma unroll
  for (int j = 0; j < 4; ++j) {
    const int idx = j * 2048 + threadIdx.x * 8;
    const int c = g * 16 + (idx >> 9);
    const float sc = gw[c] * rstd;
    const float sh = gb[c] - mean * sc;
    u16 o[8];
#pragma unroll
    for (int e = 0; e < 8; ++e) o[e] = f2bf(xs[idx + e] * sc + sh);
    *reinterpret_cast<uint4*>(xn + (size_t)bg * 8192 + idx) = *reinterpret_cast<const uint4*>(o);
  }
}

// ---------- fp32 -> bf16 cast for the 3 weight matrices ----------
__global__ __launch_bounds__(256) void cast3_k(const float* __restrict__ a,
                                               const float* __restrict__ b2,
                                               const float* __restrict__ c,
                                               u16* __restrict__ oa, u16* __restrict__ ob,
                                               u16* __restrict__ oc) {
  const int which = blockIdx.x >> 7;
  const float* in = which == 0 ? a : (which == 1 ? b2 : c);
  u16* out = which == 0 ? oa : (which == 1 ? ob : oc);
  size_t base = (((size_t)(blockIdx.x & 127)) * 256 + threadIdx.x) * 8;
  float4 v0 = *reinterpret_cast<const float4*>(in + base);
  float4 v1 = *reinterpret_cast<const float4*>(in + base + 4);
  u16 o[8];
  o[0] = f2bf(v0.x); o[1] = f2bf(v0.y); o[2] = f2bf(v0.z); o[3] = f2bf(v0.w);
  o[4] = f2bf(v1.x); o[5] = f2bf(v1.y); o[6] = f2bf(v1.z); o[7] = f2bf(v1.w);
  *reinterpret_cast<uint4*>(out + base) = *reinterpret_cast<const uint4*>(o);
}

// ---------- Batched GEMM: out[b,m,n] = sum_k A[m,k]*B[n,k] (+bias) ----------
// 128x128 tile, 4 waves (64x64 each), swizzled LDS, depth-2 counted vmcnt.
// OUT_MODE: 0 = bf16 out + bias[n]; 1 = bf16 out + bias[m]; 2 = f32 out, no bias.
template <int OUT_MODE>
__global__ __launch_bounds__(256, 2) void gemm_abt_k(const u16* __restrict__ A, size_t sA,
                                                     const u16* __restrict__ Bm, size_t sB,
                                                     const float* __restrict__ bias,
                                                     void* __restrict__ out, size_t sO) {
  __shared__ u16 As[2][4096];
  __shared__ u16 Bs[2][4096];     // 32 KB total
  const int d = blockIdx.x;
  const int t = d >> 3;
  const int b = (d & 7) * 8 + (t >> 4);          // XCD-bijective batch
  const int tile = t & 15;
  const int tm = (tile >> 2) * 128, tn = (tile & 3) * 128;
  const u16* Ab = A + (size_t)b * sA;
  const u16* Bb = Bm + (size_t)b * sB;
  const int tid = threadIdx.x, w = tid >> 6, lane = tid & 63;
  const int wr = (w >> 1) * 64, wc = (w & 1) * 64;
  const int srow = lane >> 2;
  const int ssw = ((lane & 3) ^ ((lane >> 3) & 3)) * 8;   // inverse-swizzled src col
  f32x4 acc[4][4] = {};

#define GM_STAGE(bb, k0)                                                       \
  {                                                                            \
    _Pragma("unroll")                                                          \
    for (int s2 = 0; s2 < 4; ++s2) {                                           \
      const int c = w * 4 + s2;                                                \
      if (c < 8)                                                               \
        gload_lds16(Ab + (size_t)(tm + c * 16 + srow) * 512 + (k0) + ssw,      \
                    &As[bb][c * 512]);                                         \
      else                                                                     \
        gload_lds16(Bb + (size_t)(tn + (c - 8) * 16 + srow) * 512 + (k0) + ssw,\
                    &Bs[bb][(c - 8) * 512]);                                   \
    }                                                                          \
  }

  GM_STAGE(0, 0);       // 4 loads/thread
  GM_STAGE(1, 32);      // 8 in flight
  for (int ts = 0; ts < 16; ++ts) {
    const int cur = ts & 1;
    WAIT_ENTER(4, ts == 15);
    const int frow = lane & 15, cc = lane >> 4;
    short8 af[4], bf[4];
#pragma unroll
    for (int i = 0; i < 4; ++i) {
      af[i] = *lds_frag(As[cur], wr + i * 16 + frow, cc);
      bf[i] = *lds_frag(Bs[cur], wc + i * 16 + frow, cc);
    }
#pragma unroll
    for (int mi = 0; mi < 4; ++mi)
#pragma unroll
      for (int ni = 0; ni < 4; ++ni)
        acc[mi][ni] = mfma16(af[mi], bf[ni], acc[mi][ni]);
    WAIT_EXIT();
    if (ts < 14) GM_STAGE(cur, (ts + 2) * 32);
  }
#undef GM_STAGE

  const int col0 = lane & 15, row0 = (lane >> 4) * 4;
#pragma unroll
  for (int mi = 0; mi < 4; ++mi)
#pragma unroll
    for (int ni = 0; ni < 4; ++ni) {
      const int gc = tn + wc + ni * 16 + col0;
      const float bv = (OUT_MODE == 0) ? bias[gc] : 0.f;
#pragma unroll
      for (int r = 0; r < 4; ++r) {
        const int gr = tm + wr + mi * 16 + row0 + r;
        float v = acc[mi][ni][r];
        if (OUT_MODE == 0) v += bv;
        if (OUT_MODE == 1) v += bias[gr];
        if (OUT_MODE == 2)
          ((float*)out)[(size_t)b * sO + (size_t)gr * 512 + gc] = v;
        else
          ((u16*)out)[(size_t)b * sO + (size_t)gr * 512 + gc] = f2bf(v);
      }
    }
}

// ---------- scores + softmax -> P: 8 waves = 2 qhalf x 4 kquad (unchanged R7) ----------
__global__ __launch_bounds__(512, 2) void scores_softmax_k(const u16* __restrict__ Q,
                                                           const u16* __restrict__ K,
                                                           u16* __restrict__ P) {
  __shared__ u16 Qs[2][4096];
  __shared__ u16 Ks[2][16384];
  __shared__ float rmax[4][128], rsum[4][128];
  const int d = blockIdx.x;       // 0..255
  const int t = d >> 3;
  const int b = (d & 7) * 8 + (t >> 2);
  const int m0 = (t & 3) * 128;
  const u16* Qb = Q + (size_t)b * 262144 + (size_t)m0 * 512;
  const u16* Kb = K + (size_t)b * 262144;
  u16* Pb = P + (size_t)b * 262144;
  const int tid = threadIdx.x, wid = tid >> 6, lane = tid & 63;
  const int qh = wid >> 2, kq = wid & 3;
  const int srow = lane >> 2;
  const int ssw = ((lane & 3) ^ ((lane >> 3) & 3)) * 8;
  f32x4 acc[4][8] = {};

#define SC_STAGE(bb, k0)                                                       \
  {                                                                            \
    _Pragma("unroll")                                                          \
    for (int s2 = 0; s2 < 5; ++s2) {                                           \
      const int c = wid * 5 + s2;                                              \
      if (c < 8)                                                               \
        gload_lds16(Qb + (size_t)(c * 16 + srow) * 512 + (k0) + ssw,           \
                    &Qs[bb][c * 512]);                                         \
      else                                                                     \
        gload_lds16(Kb + (size_t)((c - 8) * 16 + srow) * 512 + (k0) + ssw,     \
                    &Ks[bb][(c - 8) * 512]);                                   \
    }                                                                          \
  }

  SC_STAGE(0, 0);
  SC_STAGE(1, 32);
  for (int ts = 0; ts < 16; ++ts) {
    const int cur = ts & 1;
    WAIT_ENTER(5, ts == 15);
    const int frow = lane & 15, cc = lane >> 4;
    short8 aq[4];
#pragma unroll
    for (int i = 0; i < 4; ++i)
      aq[i] = *lds_frag(Qs[cur], qh * 64 + i * 16 + frow, cc);
#pragma unroll
    for (int j = 0; j < 8; ++j) {
      short8 bk = *lds_frag(Ks[cur], kq * 128 + j * 16 + frow, cc);
#pragma unroll
      for (int i = 0; i < 4; ++i)
        acc[i][j] = mfma16(aq[i], bk, acc[i][j]);
    }
    WAIT_EXIT();
    if (ts < 14) SC_STAGE(cur, (ts + 2) * 32);
  }
#undef SC_STAGE

  float pm[4][4];
#pragma unroll
  for (int i = 0; i < 4; ++i)
#pragma unroll
    for (int r = 0; r < 4; ++r) pm[i][r] = -1e30f;
#pragma unroll
  for (int i = 0; i < 4; ++i)
#pragma unroll
    for (int j = 0; j < 8; ++j)
#pragma unroll
      for (int r = 0; r < 4; ++r) {
        float v = acc[i][j][r] * SM_SCALE;
        acc[i][j][r] = v;
        pm[i][r] = fmaxf(pm[i][r], v);
      }
#pragma unroll
  for (int off = 1; off < 16; off <<= 1)
#pragma unroll
    for (int i = 0; i < 4; ++i)
#pragma unroll
      for (int r = 0; r < 4; ++r) pm[i][r] = fmaxf(pm[i][r], __shfl_xor(pm[i][r], off));
  if ((lane & 15) == 0) {
#pragma unroll
    for (int i = 0; i < 4; ++i)
#pragma unroll
      for (int r = 0; r < 4; ++r)
        rmax[kq][qh * 64 + i * 16 + (lane >> 4) * 4 + r] = pm[i][r];
  }
  __syncthreads();
#pragma unroll
  for (int i = 0; i < 4; ++i)
#pragma unroll
    for (int r = 0; r < 4; ++r) {
      const int row = qh * 64 + i * 16 + (lane >> 4) * 4 + r;
      pm[i][r] = fmaxf(fmaxf(rmax[0][row], rmax[1][row]), fmaxf(rmax[2][row], rmax[3][row]));
    }
  float ps[4][4];
#pragma unroll
  for (int i = 0; i < 4; ++i)
#pragma unroll
    for (int r = 0; r < 4; ++r) ps[i][r] = 0.f;
#pragma unroll
  for (int i = 0; i < 4; ++i)
#pragma unroll
    for (int j = 0; j < 8; ++j)
#pragma unroll
      for (int r = 0; r < 4; ++r) {
        float e = __expf(acc[i][j][r] - pm[i][r]);
        acc[i][j][r] = e;
        ps[i][r] += e;
      }
#pragma unroll
  for (int off = 1; off < 16; off <<= 1)
#pragma unroll
    for (int i = 0; i < 4; ++i)
#pragma unroll
      for (int r = 0; r < 4; ++r) ps[i][r] += __shfl_xor(ps[i][r], off);
  if ((lane & 15) == 0) {
#pragma unroll
    for (int i = 0; i < 4; ++i)
#pragma unroll
      for (int r = 0; r < 4; ++r)
        rsum[kq][qh * 64 + i * 16 + (lane >> 4) * 4 + r] = ps[i][r];
  }
  __syncthreads();
#pragma unroll
  for (int i = 0; i < 4; ++i)
#pragma unroll
    for (int r = 0; r < 4; ++r) {
      const int row = qh * 64 + i * 16 + (lane >> 4) * 4 + r;
      ps[i][r] = 1.0f / (rsum[0][row] + rsum[1][row] + rsum[2][row] + rsum[3][row]);
    }
#pragma unroll
  for (int i = 0; i < 4; ++i)
#pragma unroll
    for (int j = 0; j < 8; ++j) {
      const int gcol = kq * 128 + j * 16 + (lane & 15);
#pragma unroll
      for (int r = 0; r < 4; ++r) {
        const int grow = m0 + qh * 64 + i * 16 + (lane >> 4) * 4 + r;
        Pb[(size_t)grow * 512 + gcol] = f2bf(acc[i][j][r] * ps[i][r]);
      }
    }
}

extern "C" void kernel_launch(void* const* d_in, const int* in_sizes, int n_in,
                              void* d_out, int out_size, void* d_ws, size_t ws_size,
                              hipStream_t stream) {
  const float* x = (const float*)d_in[0];
  const float* qw = (const float*)d_in[1];
  const float* qb = (const float*)d_in[2];
  const float* kw = (const float*)d_in[3];
  const float* kb = (const float*)d_in[4];
  const float* vw = (const float*)d_in[5];
  const float* vb = (const float*)d_in[6];
  const float* gnw = (const float*)d_in[7];
  const float* gnb = (const float*)d_in[8];

  char* ws = (char*)d_ws;
  u16* qwb = (u16*)(ws);
  u16* kwb = (u16*)(ws + 524288);
  u16* vwb = (u16*)(ws + 2 * 524288);
  u16* xn = (u16*)(ws + 4 * 524288);
  u16* Qb = xn + 16777216;
  u16* Kb = Qb + 16777216;
  u16* VT = Kb + 16777216;
  u16* P = xn;                       // xn dead after QKV
  float* out = (float*)d_out;

  gn_fused_k<<<dim3(2048), dim3(256), 0, stream>>>(x, gnw, gnb, xn);
  cast3_k<<<dim3(384), dim3(256), 0, stream>>>(qw, kw, vw, qwb, kwb, vwb);
  // Q = xn qw^T + qb ; K = xn kw^T + kb (bf16, col bias)
  gemm_abt_k<0><<<dim3(1024), dim3(256), 0, stream>>>(xn, (size_t)262144, qwb, (size_t)0, qb, (void*)Qb, (size_t)262144);
  gemm_abt_k<0><<<dim3(1024), dim3(256), 0, stream>>>(xn, (size_t)262144, kwb, (size_t)0, kb, (void*)Kb, (size_t)262144);
  // VT[b,d,c] = sum_k vw[d,k] xn[c,k] + vb[d] (bf16, row bias)
  gemm_abt_k<1><<<dim3(1024), dim3(256), 0, stream>>>(vwb, (size_t)0, xn, (size_t)262144, vb, (void*)VT, (size_t)262144);
  // P = softmax(Q K^T * scale)
  scores_softmax_k<<<dim3(256), dim3(512), 0, stream>>>(Qb, Kb, P);
  // out[b,m,n] = sum_k P[m,k] VT[n,k] (f32)
  gemm_abt_k<2><<<dim3(1024), dim3(256), 0, stream>>>(P, (size_t)262144, VT, (size_t)262144, (const float*)nullptr, (void*)out, (size_t)262144);
}